// Round 17
// baseline (301.793 us; speedup 1.0000x reference)
//
#include <hip/hip_runtime.h>
#include <cstddef>

// Problem constants (from reference)
#define BB   16
#define HHY  128
#define WWX  256
#define CC   64
#define DDp  12
#define HOUT 1024
#define WOUT 2048

typedef _Float16 hf;                                        // storage type
typedef __fp16 h2 __attribute__((ext_vector_type(2)));      // builtin reg pair

__device__ __forceinline__ h2 u2h(unsigned u) { return __builtin_bit_cast(h2, u); }
__device__ __forceinline__ unsigned pkrtz(float a, float b) {
  return __builtin_bit_cast(unsigned, __builtin_amdgcn_cvt_pkrtz(a, b));
}

#if defined(__has_builtin)
#if __has_builtin(__builtin_amdgcn_fdot2)
#define FDOT2(a, b, c) __builtin_amdgcn_fdot2((a), (b), (c), false)
#endif
#endif
#ifndef FDOT2
#define FDOT2(a, b, c) ((float)(a)[0] * (float)(b)[0] + (float)(a)[1] * (float)(b)[1] + (c))
#endif

// |a-b| dot (1,1) accumulated into c (packed fp16 pairs, f32 accum).
__device__ __forceinline__ float adot(unsigned lu, unsigned ru, float c) {
  const h2 d = u2h(lu) - u2h(ru);
  const unsigned au = __builtin_bit_cast(unsigned, d) & 0x7FFF7FFFu;
  return FDOT2(u2h(au), u2h(0x3C003C00u), c);
}

// ---------------------------------------------------------------------------
// prep: convert conv weights to fp16, repacked [tap27][co][ci] so the ci pairs
// consumed by v_dot2_f32_f16 are contiguous. w1,w2,w3: 432 each; wf: 108.
// ---------------------------------------------------------------------------
__global__ __launch_bounds__(256) void prep_k(const float* __restrict__ w1,
                                              const float* __restrict__ w2,
                                              const float* __restrict__ w3,
                                              const float* __restrict__ wf,
                                              hf* __restrict__ o) {
  const int t = threadIdx.x;
  for (int i = t; i < 432; i += 256) {
    const int t27 = i >> 4;
    const int ci = (i >> 2) & 3;
    const int co = i & 3;
    const int dst = (t27 * 4 + co) * 4 + ci;
    o[dst]       = (hf)w1[i];
    o[432 + dst] = (hf)w2[i];
    o[864 + dst] = (hf)w3[i];
  }
  for (int i = t; i < 108; i += 256) o[1296 + i] = (hf)wf[i];  // [t27][ci], COUT=1
}

// ---------------------------------------------------------------------------
// Kernel 1: cost volume (f32 out). cost[b,h,w,d] = sum_c |L[b,h,w,c]-R[b,h,w-d,c]|
// (zero-pad shift handled by zero-filled R halo rows: w<d reads zeros -> sum|L|).
// PERSISTENT + DOUBLE-BUFFERED. Grid = 1024 blocks (4/CU at 40 KB LDS, all
// resident); each block runs 8 consecutive tiles (same (b,h) rows first ->
// R-halo L2 reuse). Next tile's 9 float4 loads are issued right after the
// staging barrier and held in registers across the current tile's compute.
// (r16 bug: cv_issue call sites swapped t<->tau -> garbage staging. Fixed:
// signature is now (L, R, tau, t, pre) matching the call order.)
// Tile: 64 w x 12 d; 256 threads = 64 w x 4 dgroups, 3 outputs each.
// Output transpose at stride 13 (odd -> 2-way banks, free).
// ---------------------------------------------------------------------------
#define CVS 36        // LDS row stride (dwords): 32 data + 4 pad
#define CVHALO 11
#define CVWT 64
#define CVROWS (CVWT + CVHALO + CVWT)  // 75 R rows + 64 L rows = 139
#define CVTILES 8

__device__ __forceinline__ void cv_issue(const float* __restrict__ L,
                                         const float* __restrict__ R,
                                         int tau, int t, float4* pre) {
  const int wt = tau & 3;
  const int hh = (tau >> 2) & (HHY - 1);
  const int bb = tau >> 9;
  const size_t rowbase = ((size_t)(bb * HHY + hh)) * WWX;
  const float* Lrow = L + rowbase * CC;
  const float* Rrow = R + rowbase * CC;
  const int wb = wt * CVWT;
#pragma unroll
  for (int j = 0; j < 9; ++j) {
    const int fi = t + 256 * j;          // float4 id in [0, 2224)
    float4 v = make_float4(0.f, 0.f, 0.f, 0.f);
    if (fi < CVROWS * 16) {
      const int row = fi >> 4;
      const int f4 = fi & 15;
      if (row < CVWT + CVHALO) {
        const int gw = wb - CVHALO + row;
        if (gw >= 0) v = *(const float4*)(Rrow + (size_t)gw * CC + 4 * f4);
      } else {
        const int gw = wb + row - (CVWT + CVHALO);
        v = *(const float4*)(Lrow + (size_t)gw * CC + 4 * f4);
      }
    }
    pre[j] = v;
  }
}

__global__ __launch_bounds__(256) void cost_volume_k(const float* __restrict__ L,
                                                     const float* __restrict__ R,
                                                     float* __restrict__ cost) {
  __shared__ unsigned ls[2 * CVROWS * CVS];   // 2 x 20016 B = 40032 B
  const int t = threadIdx.x;
  const int w = t & 63;
  const int dg = t >> 6;                 // wave-uniform

  float4 pre[9];
  cv_issue(L, R, blockIdx.x * CVTILES, t, pre);  // prologue: tile 0

  for (int k = 0; k < CVTILES; ++k) {
    const int tau = blockIdx.x * CVTILES + k;
    unsigned* buf = &ls[(k & 1) * CVROWS * CVS];

    // stage prefetched regs -> LDS (fp16 pairs)
#pragma unroll
    for (int j = 0; j < 9; ++j) {
      const int fi = t + 256 * j;
      if (fi < CVROWS * 16) {
        const int row = fi >> 4;
        const int f4 = fi & 15;
        *(uint2*)(&buf[row * CVS + f4 * 2]) =
            make_uint2(pkrtz(pre[j].x, pre[j].y), pkrtz(pre[j].z, pre[j].w));
      }
    }
    __syncthreads();

    // issue next tile's loads; they fly during this tile's compute
    if (k + 1 < CVTILES) cv_issue(L, R, tau + 1, t, pre);

    // compute: d = dg, dg+4, dg+8; R row = w + 11 - d (halo rows zeroed)
    const int rb0 = (w + CVHALO - dg) * CVS;
    const int rb1 = rb0 - 4 * CVS;
    const int rb2 = rb0 - 8 * CVS;
    const int rbL = (CVWT + CVHALO + w) * CVS;

    float a0 = 0.f, a1 = 0.f, a2 = 0.f;
#pragma unroll
    for (int kk = 0; kk < 8; ++kk) {
      const uint4 lq = *(const uint4*)(&buf[rbL + 4 * kk]);
      const uint4 r0 = *(const uint4*)(&buf[rb0 + 4 * kk]);
      a0 = adot(lq.x, r0.x, a0); a0 = adot(lq.y, r0.y, a0);
      a0 = adot(lq.z, r0.z, a0); a0 = adot(lq.w, r0.w, a0);
      const uint4 r1 = *(const uint4*)(&buf[rb1 + 4 * kk]);
      a1 = adot(lq.x, r1.x, a1); a1 = adot(lq.y, r1.y, a1);
      a1 = adot(lq.z, r1.z, a1); a1 = adot(lq.w, r1.w, a1);
      const uint4 r2 = *(const uint4*)(&buf[rb2 + 4 * kk]);
      a2 = adot(lq.x, r2.x, a2); a2 = adot(lq.y, r2.y, a2);
      a2 = adot(lq.z, r2.z, a2); a2 = adot(lq.w, r2.w, a2);
    }

    // transpose through LDS (stride 13: odd -> 2-way banks) + coalesced store
    __syncthreads();                     // compute reads of buf done
    float* lo = (float*)buf;
    lo[w * 13 + dg]     = a0;
    lo[w * 13 + dg + 4] = a1;
    lo[w * 13 + dg + 8] = a2;
    __syncthreads();
    if (t < CVWT * DDp / 4) {            // 192 float4
      const int wq = t / 3;
      const int q  = t - wq * 3;
      const float4 v = *(const float4*)(&lo[wq * 13 + 4 * q]);
      const int wt = tau & 3;
      const int hh = (tau >> 2) & (HHY - 1);
      const int bb = tau >> 9;
      const size_t rowbase = ((size_t)(bb * HHY + hh)) * WWX;
      *(float4*)(cost + (rowbase + wt * CVWT) * DDp + 4 * t) = v;
    }
    __syncthreads();                     // stores' LDS reads done before reuse
  }
}

// ---------------------------------------------------------------------------
// conv0: 3x3x3, CIN=1 (f32 cost) -> COUT=4 (fp16 out). Block = one (b,h) row
// (XCD h-remap), thread = w. Row staged f32 in LDS stride 20; weights (108 f)
// wave-uniform global loads; fp16 pack on store. (Round-10 version — best.)
// ---------------------------------------------------------------------------
__global__ __launch_bounds__(256) void conv0_k(const float* __restrict__ x,
                                               const float* __restrict__ wt,
                                               const float* __restrict__ bs,
                                               hf* __restrict__ y) {
  constexpr int S = 20;
  __shared__ float ls[WWX * S];   // 20 KB
  const int t = threadIdx.x;
  const int id = blockIdx.x;
  const int h = ((id & 7) << 4) | ((id >> 3) & 15);  // XCD-contiguous h chunks
  const int b = id >> 7;

  float acc[DDp][4];
#pragma unroll
  for (int co = 0; co < 4; ++co) {
    const float bv = bs[co];
#pragma unroll
    for (int d = 0; d < DDp; ++d) acc[d][co] = bv;
  }

#pragma unroll
  for (int kh = 0; kh < 3; ++kh) {
    const int hh = h + kh - 1;
    if (hh < 0 || hh >= HHY) continue;  // block-uniform

    __syncthreads();
    const float* xr = x + ((size_t)(b * HHY + hh) * WWX) * DDp;
#pragma unroll
    for (int j = 0; j < 3; ++j) {
      const int fi4 = t + 256 * j;     // [0,768)
      const int w_ = fi4 / 3;
      const int k_ = fi4 - w_ * 3;
      *(float4*)(&ls[w_ * S + k_ * 4]) = ((const float4*)xr)[fi4];
    }
    __syncthreads();

#pragma unroll
    for (int kw = 0; kw < 3; ++kw) {
      const int ww = t + kw - 1;
      if (ww < 0 || ww >= WWX) continue;
      const float* lp = &ls[ww * S];

      const float* wp = wt + (size_t)(kh * 3 + kw) * 12;
      float wr[12];
#pragma unroll
      for (int i = 0; i < 12; ++i) wr[i] = wp[i];

      float v[DDp];
#pragma unroll
      for (int k = 0; k < 3; ++k)
        ((float4*)v)[k] = *(const float4*)(lp + 4 * k);
#pragma unroll
      for (int vo = 0; vo < DDp; ++vo)
#pragma unroll
        for (int kd = 0; kd < 3; ++kd) {
          const int d = vo + 1 - kd;
          if (d < 0 || d >= DDp) continue;
#pragma unroll
          for (int co = 0; co < 4; ++co)
            acc[d][co] += v[vo] * wr[kd * 4 + co];
        }
    }
  }

  unsigned ov[DDp * 2];
#pragma unroll
  for (int d = 0; d < DDp; ++d) {
    ov[d * 2]     = pkrtz(fmaxf(acc[d][0], 0.f), fmaxf(acc[d][1], 0.f));
    ov[d * 2 + 1] = pkrtz(fmaxf(acc[d][2], 0.f), fmaxf(acc[d][3], 0.f));
  }
  uint4* yp = (uint4*)(y + ((size_t)(b * HHY + h) * WWX + t) * (DDp * 4));
#pragma unroll
  for (int i = 0; i < 6; ++i) yp[i] = ((uint4*)ov)[i];
}

// ---------------------------------------------------------------------------
// Mid/final conv3d 3x3x3, CIN=4, fp16 activations [B,H,W,D,4], f32 accumulate
// via v_dot2_f32_f16. Block = one (b,h) row (XCD h-remap), thread = w. Rows
// staged fp16 in LDS (26-uint stride; 26.6 KB -> 6 blocks/CU). Weights fp16
// repacked [tap][co][ci], wave-uniform scalar loads. (Round-10 version.)
// FUSE_SM: COUT=1 final conv + softmax(-cost) + disparity regression.
// ---------------------------------------------------------------------------
template <int COUT, bool FUSE_SM>
__global__ __launch_bounds__(256) void convh_k(const hf* __restrict__ x,
                                               const hf* __restrict__ wh,
                                               const float* __restrict__ bs,
                                               void* __restrict__ yv) {
  constexpr int DCH = DDp * 4;        // 48 halves per w
  constexpr int SU  = 26;             // LDS stride per w in uints (52 halves)
  __shared__ unsigned lsu[WWX * SU];  // 26624 B

  const int t = threadIdx.x;
  const int id = blockIdx.x;
  const int h = ((id & 7) << 4) | ((id >> 3) & 15);
  const int b = id >> 7;

  float acc[DDp][COUT];
#pragma unroll
  for (int co = 0; co < COUT; ++co) {
    const float bv = bs[co];
#pragma unroll
    for (int d = 0; d < DDp; ++d) acc[d][co] = bv;
  }

  const unsigned* whu = (const unsigned*)wh;

#pragma unroll
  for (int kh = 0; kh < 3; ++kh) {
    const int hh = h + kh - 1;
    if (hh < 0 || hh >= HHY) continue;  // block-uniform

    __syncthreads();
    const uint4* xr = (const uint4*)(x + (size_t)(b * HHY + hh) * WWX * DCH);
#pragma unroll
    for (int j = 0; j < 6; ++j) {
      const int fi4 = t + 256 * j;     // [0,1536)
      const int w_ = fi4 / 6;
      const int k_ = fi4 - w_ * 6;
      const uint4 v = xr[fi4];
      unsigned* dst = &lsu[w_ * SU + k_ * 4];
      *(uint2*)(dst)     = make_uint2(v.x, v.y);
      *(uint2*)(dst + 2) = make_uint2(v.z, v.w);
    }
    __syncthreads();

#pragma unroll
    for (int kw = 0; kw < 3; ++kw) {
      const int ww = t + kw - 1;
      if (ww < 0 || ww >= WWX) continue;  // divergent only at row edges

      // per-tap fp16 weights, wave-uniform scalar loads
      unsigned w01[3][COUT], w23[3][COUT];
      const int tap3 = (kh * 3 + kw) * 3;
#pragma unroll
      for (int kd = 0; kd < 3; ++kd)
#pragma unroll
        for (int co = 0; co < COUT; ++co) {
          const int u0 = ((tap3 + kd) * COUT + co) * 2;
          w01[kd][co] = whu[u0];
          w23[kd][co] = whu[u0 + 1];
        }

      const unsigned* lp = &lsu[ww * SU];
#pragma unroll
      for (int vo = 0; vo < DDp; ++vo) {
        const uint2 xu = *(const uint2*)(lp + vo * 2);
        const h2 x01 = u2h(xu.x), x23 = u2h(xu.y);
#pragma unroll
        for (int kd = 0; kd < 3; ++kd) {
          const int d = vo + 1 - kd;
          if (d < 0 || d >= DDp) continue;
#pragma unroll
          for (int co = 0; co < COUT; ++co)
            acc[d][co] = FDOT2(x01, u2h(w01[kd][co]),
                         FDOT2(x23, u2h(w23[kd][co]), acc[d][co]));
        }
      }
    }
  }

  if constexpr (FUSE_SM) {
    float* y = (float*)yv;
    float mn = acc[0][0];
#pragma unroll
    for (int d = 1; d < DDp; ++d) mn = fminf(mn, acc[d][0]);
    float s = 0.f, sw = 0.f;
#pragma unroll
    for (int d = 0; d < DDp; ++d) {
      const float e = __expf(mn - acc[d][0]);
      s += e;
      sw += e * (float)d;
    }
    y[(size_t)(b * HHY + h) * WWX + t] = sw / s;
  } else {
    hf* y = (hf*)yv;
    unsigned ov[DDp * 2];
#pragma unroll
    for (int d = 0; d < DDp; ++d) {
      ov[d * 2]     = pkrtz(fmaxf(acc[d][0], 0.f), fmaxf(acc[d][1 % COUT], 0.f));
      ov[d * 2 + 1] = pkrtz(fmaxf(acc[d][2 % COUT], 0.f), fmaxf(acc[d][3 % COUT], 0.f));
    }
    uint4* yp = (uint4*)(y + ((size_t)(b * HHY + h) * WWX + t) * DCH);
#pragma unroll
    for (int i = 0; i < 6; ++i) yp[i] = ((uint4*)ov)[i];
  }
}

// ---------------------------------------------------------------------------
// 8x bilinear upsample, 4 outputs per thread (2 input cols x 2 rows -> 4 loads,
// 1 float4 store). jax half-pixel convention; edge renorm == index clamp.
// ---------------------------------------------------------------------------
__global__ __launch_bounds__(256) void resize4_k(const float* __restrict__ pred,
                                                 float* __restrict__ out) {
  const int idx = blockIdx.x * 256 + threadIdx.x;
  const int xg = idx & 511;
  const int y = (idx >> 9) & 1023;
  const int b = idx >> 19;

  const int parity = xg & 1;
  const int m = xg >> 1;
  const int x0 = m - 1 + parity;
  const int x0c = max(x0, 0);
  const int x1c = min(x0 + 1, WWX - 1);
  const float wx0 = (parity ? 0.0625f : 0.5625f);

  const int py = y & 7;
  const int my = y >> 3;
  const int y0 = my - 1 + (py >= 4 ? 1 : 0);
  const float wy = (py >= 4) ? 0.0625f + (py - 4) * 0.125f : 0.5625f + py * 0.125f;
  const int y0c = max(y0, 0);
  const int y1c = min(y0 + 1, HHY - 1);

  const float* pb = pred + (size_t)b * HHY * WWX;
  const float a = pb[y0c * WWX + x0c];
  const float bv = pb[y0c * WWX + x1c];
  const float c = pb[y1c * WWX + x0c];
  const float d = pb[y1c * WWX + x1c];

  const float top0 = a + (bv - a) * wx0;
  const float bot0 = c + (d - c) * wx0;
  const float dtop = (bv - a) * 0.125f;
  const float dbot = (d - c) * 0.125f;

  float4 o;
  o.x = top0 + wy * (bot0 - top0);
  o.y = (top0 + dtop) + wy * ((bot0 + dbot) - (top0 + dtop));
  o.z = (top0 + 2.f * dtop) + wy * ((bot0 + 2.f * dbot) - (top0 + 2.f * dtop));
  o.w = (top0 + 3.f * dtop) + wy * ((bot0 + 3.f * dbot) - (top0 + 3.f * dtop));

  *(float4*)(out + (size_t)idx * 4) = o;
}

// ---------------------------------------------------------------------------
extern "C" void kernel_launch(void* const* d_in, const int* in_sizes, int n_in,
                              void* d_out, int out_size, void* d_ws, size_t ws_size,
                              hipStream_t stream) {
  const float* feat_l = (const float*)d_in[0];
  const float* feat_r = (const float*)d_in[1];
  const float* w0 = (const float*)d_in[2];
  const float* b0 = (const float*)d_in[3];
  const float* w1 = (const float*)d_in[4];
  const float* b1 = (const float*)d_in[5];
  const float* w2 = (const float*)d_in[6];
  const float* b2 = (const float*)d_in[7];
  const float* w3 = (const float*)d_in[8];
  const float* b3 = (const float*)d_in[9];
  const float* wf = (const float*)d_in[10];
  const float* bf = (const float*)d_in[11];
  float* out = (float*)d_out;

  // ws layout: A,B = fp16 activation ping-pong [B,H,W,D,4] (50.3 MB each);
  // C = f32 cost volume (25.2 MB); P = f32 pred (2.1 MB); Wh = fp16 weights.
  char* ws = (char*)d_ws;
  hf*    A  = (hf*)ws;
  hf*    Bf = (hf*)(ws + 50331648);
  float* C  = (float*)(ws + 100663296);
  float* P  = (float*)(ws + 125829120);
  hf*    Wh = (hf*)(ws + 127926272);

  dim3 blk(256);
  prep_k<<<dim3(1), blk, 0, stream>>>(w1, w2, w3, wf, Wh);
  cost_volume_k<<<dim3(BB * HHY * (WWX / CVWT) / CVTILES), blk, 0, stream>>>(feat_l, feat_r, C);
  conv0_k<<<dim3(HHY * BB), blk, 0, stream>>>(C, w0, b0, A);
  convh_k<4, false><<<dim3(HHY * BB), blk, 0, stream>>>(A,  Wh,        b1, Bf);
  convh_k<4, false><<<dim3(HHY * BB), blk, 0, stream>>>(Bf, Wh + 432,  b2, A);
  convh_k<4, false><<<dim3(HHY * BB), blk, 0, stream>>>(A,  Wh + 864,  b3, Bf);
  convh_k<1, true ><<<dim3(HHY * BB), blk, 0, stream>>>(Bf, Wh + 1296, bf, P);

  const int ngroups = BB * HOUT * (WOUT / 4);
  resize4_k<<<dim3(ngroups / 256), blk, 0, stream>>>(P, out);
}

// Round 18
// 299.802 us; speedup vs baseline: 1.0066x; 1.0066x over previous
//
#include <hip/hip_runtime.h>
#include <cstddef>

// Problem constants (from reference)
#define BB   16
#define HHY  128
#define WWX  256
#define CC   64
#define DDp  12
#define HOUT 1024
#define WOUT 2048

typedef _Float16 hf;                                        // storage type
typedef __fp16 h2 __attribute__((ext_vector_type(2)));      // builtin reg pair

__device__ __forceinline__ h2 u2h(unsigned u) { return __builtin_bit_cast(h2, u); }
__device__ __forceinline__ unsigned pkrtz(float a, float b) {
  return __builtin_bit_cast(unsigned, __builtin_amdgcn_cvt_pkrtz(a, b));
}

#if defined(__has_builtin)
#if __has_builtin(__builtin_amdgcn_fdot2)
#define FDOT2(a, b, c) __builtin_amdgcn_fdot2((a), (b), (c), false)
#endif
#endif
#ifndef FDOT2
#define FDOT2(a, b, c) ((float)(a)[0] * (float)(b)[0] + (float)(a)[1] * (float)(b)[1] + (c))
#endif

// |a-b| dot (1,1) accumulated into c (packed fp16 pairs, f32 accum).
__device__ __forceinline__ float adot(unsigned lu, unsigned ru, float c) {
  const h2 d = u2h(lu) - u2h(ru);
  const unsigned au = __builtin_bit_cast(unsigned, d) & 0x7FFF7FFFu;
  return FDOT2(u2h(au), u2h(0x3C003C00u), c);
}

// ---------------------------------------------------------------------------
// prep: convert conv weights to fp16, repacked [tap27][co][ci] so the ci pairs
// consumed by v_dot2_f32_f16 are contiguous. w1,w2,w3: 432 each; wf: 108.
// ---------------------------------------------------------------------------
__global__ __launch_bounds__(256) void prep_k(const float* __restrict__ w1,
                                              const float* __restrict__ w2,
                                              const float* __restrict__ w3,
                                              const float* __restrict__ wf,
                                              hf* __restrict__ o) {
  const int t = threadIdx.x;
  for (int i = t; i < 432; i += 256) {
    const int t27 = i >> 4;
    const int ci = (i >> 2) & 3;
    const int co = i & 3;
    const int dst = (t27 * 4 + co) * 4 + ci;
    o[dst]       = (hf)w1[i];
    o[432 + dst] = (hf)w2[i];
    o[864 + dst] = (hf)w3[i];
  }
  for (int i = t; i < 108; i += 256) o[1296 + i] = (hf)wf[i];  // [t27][ci], COUT=1
}

// ---------------------------------------------------------------------------
// Kernel 1: cost volume (f32 out). cost[b,h,w,d] = sum_c |L[b,h,w,c]-R[b,h,w-d,c]|
// (zero-pad shift: w<d contributes sum_c |L|).
// r17 post-mortem quantified the wall via LITTLE'S LAW: register staging caps
// in-flight bytes at ~9 float4/wave = 144 B -> ~1.5-3 TB/s at ~375ns latency,
// matching all 11 ~100us variants. Fix: DEEP DMA QUEUES -- global_load_lds
// issues 9x1KB per wave (9.2 KB in flight/wave, 74 KB/CU at 8 waves) ->
// HBM-bound. Persistent 512 blocks x 16 tiles, double-buffered f32 tiles,
// RAW s_barrier + counted vmcnt(8) (prefetch stays in flight across
// barriers; never drain to 0 mid-loop). Rule #21 swizzle: source chunk
// sc = sl^(row&15) with linear DMA dest; reads apply same XOR -> 2-way banks
// (free). Zero-pad halo: clamped src + select sl = sum|L| (wb=0 only).
// LDS: 2x140 rows x 256 B + 2x(64x13) f32 scratch = 78,336 B -> 2 blocks/CU.
// ---------------------------------------------------------------------------
#define CVS2 64       // f32 dwords per row (256 B)
#define CVHALO 11
#define CVWT 64
#define CVREAL (CVWT + CVHALO + CVWT)   // 139 real rows (75 R + 64 L)
#define CVROWP 140                      // +1 pad row (35 groups x 64 chunks)
#define CVT2 16                         // tiles per persistent block

#define CV_ISSUE(TAU, BSEL) do {                                              \
    const int wt_ = (TAU) & 3;                                                \
    const int hh_ = ((TAU) >> 2) & (HHY - 1);                                 \
    const int bb_ = (TAU) >> 9;                                               \
    const size_t rb_ = ((size_t)(bb_ * HHY + hh_)) * WWX;                     \
    const float* Lr_ = L + rb_ * CC;                                          \
    const float* Rr_ = R + rb_ * CC;                                          \
    const int wb_ = wt_ * CVWT;                                               \
    _Pragma("unroll")                                                         \
    for (int i_ = 0; i_ < 9; ++i_) {                                          \
      const int G_ = wv * 9 + i_;                                             \
      if (G_ < 35) {                                                          \
        const int g_ = G_ * 64 + w;                                           \
        const int row_ = g_ >> 4;                                             \
        const int sl_ = g_ & 15;                                              \
        const int sc_ = sl_ ^ (row_ & 15);                                    \
        const float* src_;                                                    \
        if (row_ < CVWT + CVHALO) {                                           \
          int gw_ = wb_ - CVHALO + row_; if (gw_ < 0) gw_ = 0;                \
          src_ = Rr_ + (size_t)gw_ * CC + sc_ * 4;                            \
        } else {                                                              \
          int lr_ = row_ - (CVWT + CVHALO); if (lr_ > 63) lr_ = 63;           \
          src_ = Lr_ + (size_t)(wb_ + lr_) * CC + sc_ * 4;                    \
        }                                                                     \
        __builtin_amdgcn_global_load_lds(                                     \
            src_, &buf[(BSEL) * (CVROWP * CVS2) + G_ * 256], 16, 0, 0);       \
      }                                                                       \
    }                                                                         \
  } while (0)

__global__ __launch_bounds__(256) void cost_volume_k(const float* __restrict__ L,
                                                     const float* __restrict__ R,
                                                     float* __restrict__ cost) {
  __shared__ __align__(16) float buf[2 * CVROWP * CVS2];   // 71,680 B
  __shared__ float lot[2 * CVWT * 13];                      // 6,656 B
  const int t = threadIdx.x;
  const int w = t & 63;          // lane
  const int dg = t >> 6;         // d-group (== wave id)
  const int wv = dg;
  const int base = blockIdx.x * CVT2;

  CV_ISSUE(base, 0);             // prologue: tile 0 -> buf 0

  for (int k = 0; k < CVT2; ++k) {
    const int tau = base + k;

    if (k + 1 < CVT2) {
      CV_ISSUE(tau + 1, (k + 1) & 1);   // prefetch stays in flight
      asm volatile("s_waitcnt vmcnt(8)" ::: "memory");  // tile k fully landed
    } else {
      asm volatile("s_waitcnt vmcnt(0)" ::: "memory");
    }
    __builtin_amdgcn_s_barrier();       // B1: tile k visible to all waves

    const float* bp = &buf[(k & 1) * (CVROWP * CVS2)];
    const int r0 = w + CVHALO - dg;     // rows 8..74 (R)
    const int r1 = r0 - 4;
    const int r2 = r0 - 8;
    const int rL = CVWT + CVHALO + w;   // rows 75..138 (L)

    float a0 = 0.f, a1 = 0.f, a2 = 0.f, sl = 0.f;
#pragma unroll
    for (int kk = 0; kk < 16; ++kk) {
      const float4 lq = *(const float4*)&bp[rL * 64 + ((kk ^ (rL & 15)) << 2)];
      const float4 q0 = *(const float4*)&bp[r0 * 64 + ((kk ^ (r0 & 15)) << 2)];
      a0 += fabsf(lq.x - q0.x) + fabsf(lq.y - q0.y) +
            fabsf(lq.z - q0.z) + fabsf(lq.w - q0.w);
      const float4 q1 = *(const float4*)&bp[r1 * 64 + ((kk ^ (r1 & 15)) << 2)];
      a1 += fabsf(lq.x - q1.x) + fabsf(lq.y - q1.y) +
            fabsf(lq.z - q1.z) + fabsf(lq.w - q1.w);
      const float4 q2 = *(const float4*)&bp[r2 * 64 + ((kk ^ (r2 & 15)) << 2)];
      a2 += fabsf(lq.x - q2.x) + fabsf(lq.y - q2.y) +
            fabsf(lq.z - q2.z) + fabsf(lq.w - q2.w);
      sl += fabsf(lq.x) + fabsf(lq.y) + fabsf(lq.z) + fabsf(lq.w);
    }

    const int wt = tau & 3;
    const int hh = (tau >> 2) & (HHY - 1);
    const int bb = tau >> 9;
    const int wg = wt * CVWT + w;       // global w
    if (wg < dg)     a0 = sl;           // zero-pad region: cost = sum|L|
    if (wg < dg + 4) a1 = sl;
    if (wg < dg + 8) a2 = sl;

    // transpose through scratch (stride 13, odd -> conflict-free) + store
    float* lo = &lot[(k & 1) * CVWT * 13];
    lo[w * 13 + dg]     = a0;
    lo[w * 13 + dg + 4] = a1;
    lo[w * 13 + dg + 8] = a2;
    asm volatile("s_waitcnt lgkmcnt(0)" ::: "memory");  // writes visible
    __builtin_amdgcn_s_barrier();       // B2: transpose complete
    if (t < CVWT * DDp / 4) {           // 192 float4
      const int wq = t / 3;
      const int q  = t - wq * 3;
      const float4 v = *(const float4*)(&lo[wq * 13 + 4 * q]);
      const size_t rowbase = ((size_t)(bb * HHY + hh)) * WWX;
      *(float4*)(cost + (rowbase + wt * CVWT) * DDp + 4 * t) = v;
    }
  }
}

// ---------------------------------------------------------------------------
// conv0: 3x3x3, CIN=1 (f32 cost) -> COUT=4 (fp16 out). Block = one (b,h) row
// (XCD h-remap), thread = w. Row staged f32 in LDS stride 20; weights (108 f)
// wave-uniform global loads; fp16 pack on store. (Round-10 version — best.)
// ---------------------------------------------------------------------------
__global__ __launch_bounds__(256) void conv0_k(const float* __restrict__ x,
                                               const float* __restrict__ wt,
                                               const float* __restrict__ bs,
                                               hf* __restrict__ y) {
  constexpr int S = 20;
  __shared__ float ls[WWX * S];   // 20 KB
  const int t = threadIdx.x;
  const int id = blockIdx.x;
  const int h = ((id & 7) << 4) | ((id >> 3) & 15);  // XCD-contiguous h chunks
  const int b = id >> 7;

  float acc[DDp][4];
#pragma unroll
  for (int co = 0; co < 4; ++co) {
    const float bv = bs[co];
#pragma unroll
    for (int d = 0; d < DDp; ++d) acc[d][co] = bv;
  }

#pragma unroll
  for (int kh = 0; kh < 3; ++kh) {
    const int hh = h + kh - 1;
    if (hh < 0 || hh >= HHY) continue;  // block-uniform

    __syncthreads();
    const float* xr = x + ((size_t)(b * HHY + hh) * WWX) * DDp;
#pragma unroll
    for (int j = 0; j < 3; ++j) {
      const int fi4 = t + 256 * j;     // [0,768)
      const int w_ = fi4 / 3;
      const int k_ = fi4 - w_ * 3;
      *(float4*)(&ls[w_ * S + k_ * 4]) = ((const float4*)xr)[fi4];
    }
    __syncthreads();

#pragma unroll
    for (int kw = 0; kw < 3; ++kw) {
      const int ww = t + kw - 1;
      if (ww < 0 || ww >= WWX) continue;
      const float* lp = &ls[ww * S];

      const float* wp = wt + (size_t)(kh * 3 + kw) * 12;
      float wr[12];
#pragma unroll
      for (int i = 0; i < 12; ++i) wr[i] = wp[i];

      float v[DDp];
#pragma unroll
      for (int k = 0; k < 3; ++k)
        ((float4*)v)[k] = *(const float4*)(lp + 4 * k);
#pragma unroll
      for (int vo = 0; vo < DDp; ++vo)
#pragma unroll
        for (int kd = 0; kd < 3; ++kd) {
          const int d = vo + 1 - kd;
          if (d < 0 || d >= DDp) continue;
#pragma unroll
          for (int co = 0; co < 4; ++co)
            acc[d][co] += v[vo] * wr[kd * 4 + co];
        }
    }
  }

  unsigned ov[DDp * 2];
#pragma unroll
  for (int d = 0; d < DDp; ++d) {
    ov[d * 2]     = pkrtz(fmaxf(acc[d][0], 0.f), fmaxf(acc[d][1], 0.f));
    ov[d * 2 + 1] = pkrtz(fmaxf(acc[d][2], 0.f), fmaxf(acc[d][3], 0.f));
  }
  uint4* yp = (uint4*)(y + ((size_t)(b * HHY + h) * WWX + t) * (DDp * 4));
#pragma unroll
  for (int i = 0; i < 6; ++i) yp[i] = ((uint4*)ov)[i];
}

// ---------------------------------------------------------------------------
// Mid/final conv3d 3x3x3, CIN=4, fp16 activations [B,H,W,D,4], f32 accumulate
// via v_dot2_f32_f16. Block = one (b,h) row (XCD h-remap), thread = w. Rows
// staged fp16 in LDS (26-uint stride; 26.6 KB -> 6 blocks/CU). Weights fp16
// repacked [tap][co][ci], wave-uniform scalar loads. (Round-10 version.)
// FUSE_SM: COUT=1 final conv + softmax(-cost) + disparity regression.
// ---------------------------------------------------------------------------
template <int COUT, bool FUSE_SM>
__global__ __launch_bounds__(256) void convh_k(const hf* __restrict__ x,
                                               const hf* __restrict__ wh,
                                               const float* __restrict__ bs,
                                               void* __restrict__ yv) {
  constexpr int DCH = DDp * 4;        // 48 halves per w
  constexpr int SU  = 26;             // LDS stride per w in uints (52 halves)
  __shared__ unsigned lsu[WWX * SU];  // 26624 B

  const int t = threadIdx.x;
  const int id = blockIdx.x;
  const int h = ((id & 7) << 4) | ((id >> 3) & 15);
  const int b = id >> 7;

  float acc[DDp][COUT];
#pragma unroll
  for (int co = 0; co < COUT; ++co) {
    const float bv = bs[co];
#pragma unroll
    for (int d = 0; d < DDp; ++d) acc[d][co] = bv;
  }

  const unsigned* whu = (const unsigned*)wh;

#pragma unroll
  for (int kh = 0; kh < 3; ++kh) {
    const int hh = h + kh - 1;
    if (hh < 0 || hh >= HHY) continue;  // block-uniform

    __syncthreads();
    const uint4* xr = (const uint4*)(x + (size_t)(b * HHY + hh) * WWX * DCH);
#pragma unroll
    for (int j = 0; j < 6; ++j) {
      const int fi4 = t + 256 * j;     // [0,1536)
      const int w_ = fi4 / 6;
      const int k_ = fi4 - w_ * 6;
      const uint4 v = xr[fi4];
      unsigned* dst = &lsu[w_ * SU + k_ * 4];
      *(uint2*)(dst)     = make_uint2(v.x, v.y);
      *(uint2*)(dst + 2) = make_uint2(v.z, v.w);
    }
    __syncthreads();

#pragma unroll
    for (int kw = 0; kw < 3; ++kw) {
      const int ww = t + kw - 1;
      if (ww < 0 || ww >= WWX) continue;  // divergent only at row edges

      // per-tap fp16 weights, wave-uniform scalar loads
      unsigned w01[3][COUT], w23[3][COUT];
      const int tap3 = (kh * 3 + kw) * 3;
#pragma unroll
      for (int kd = 0; kd < 3; ++kd)
#pragma unroll
        for (int co = 0; co < COUT; ++co) {
          const int u0 = ((tap3 + kd) * COUT + co) * 2;
          w01[kd][co] = whu[u0];
          w23[kd][co] = whu[u0 + 1];
        }

      const unsigned* lp = &lsu[ww * SU];
#pragma unroll
      for (int vo = 0; vo < DDp; ++vo) {
        const uint2 xu = *(const uint2*)(lp + vo * 2);
        const h2 x01 = u2h(xu.x), x23 = u2h(xu.y);
#pragma unroll
        for (int kd = 0; kd < 3; ++kd) {
          const int d = vo + 1 - kd;
          if (d < 0 || d >= DDp) continue;
#pragma unroll
          for (int co = 0; co < COUT; ++co)
            acc[d][co] = FDOT2(x01, u2h(w01[kd][co]),
                         FDOT2(x23, u2h(w23[kd][co]), acc[d][co]));
        }
      }
    }
  }

  if constexpr (FUSE_SM) {
    float* y = (float*)yv;
    float mn = acc[0][0];
#pragma unroll
    for (int d = 1; d < DDp; ++d) mn = fminf(mn, acc[d][0]);
    float s = 0.f, sw = 0.f;
#pragma unroll
    for (int d = 0; d < DDp; ++d) {
      const float e = __expf(mn - acc[d][0]);
      s += e;
      sw += e * (float)d;
    }
    y[(size_t)(b * HHY + h) * WWX + t] = sw / s;
  } else {
    hf* y = (hf*)yv;
    unsigned ov[DDp * 2];
#pragma unroll
    for (int d = 0; d < DDp; ++d) {
      ov[d * 2]     = pkrtz(fmaxf(acc[d][0], 0.f), fmaxf(acc[d][1 % COUT], 0.f));
      ov[d * 2 + 1] = pkrtz(fmaxf(acc[d][2 % COUT], 0.f), fmaxf(acc[d][3 % COUT], 0.f));
    }
    uint4* yp = (uint4*)(y + ((size_t)(b * HHY + h) * WWX + t) * DCH);
#pragma unroll
    for (int i = 0; i < 6; ++i) yp[i] = ((uint4*)ov)[i];
  }
}

// ---------------------------------------------------------------------------
// 8x bilinear upsample, 4 outputs per thread (2 input cols x 2 rows -> 4 loads,
// 1 float4 store). jax half-pixel convention; edge renorm == index clamp.
// ---------------------------------------------------------------------------
__global__ __launch_bounds__(256) void resize4_k(const float* __restrict__ pred,
                                                 float* __restrict__ out) {
  const int idx = blockIdx.x * 256 + threadIdx.x;
  const int xg = idx & 511;
  const int y = (idx >> 9) & 1023;
  const int b = idx >> 19;

  const int parity = xg & 1;
  const int m = xg >> 1;
  const int x0 = m - 1 + parity;
  const int x0c = max(x0, 0);
  const int x1c = min(x0 + 1, WWX - 1);
  const float wx0 = (parity ? 0.0625f : 0.5625f);

  const int py = y & 7;
  const int my = y >> 3;
  const int y0 = my - 1 + (py >= 4 ? 1 : 0);
  const float wy = (py >= 4) ? 0.0625f + (py - 4) * 0.125f : 0.5625f + py * 0.125f;
  const int y0c = max(y0, 0);
  const int y1c = min(y0 + 1, HHY - 1);

  const float* pb = pred + (size_t)b * HHY * WWX;
  const float a = pb[y0c * WWX + x0c];
  const float bv = pb[y0c * WWX + x1c];
  const float c = pb[y1c * WWX + x0c];
  const float d = pb[y1c * WWX + x1c];

  const float top0 = a + (bv - a) * wx0;
  const float bot0 = c + (d - c) * wx0;
  const float dtop = (bv - a) * 0.125f;
  const float dbot = (d - c) * 0.125f;

  float4 o;
  o.x = top0 + wy * (bot0 - top0);
  o.y = (top0 + dtop) + wy * ((bot0 + dbot) - (top0 + dtop));
  o.z = (top0 + 2.f * dtop) + wy * ((bot0 + 2.f * dbot) - (top0 + 2.f * dtop));
  o.w = (top0 + 3.f * dtop) + wy * ((bot0 + 3.f * dbot) - (top0 + 3.f * dtop));

  *(float4*)(out + (size_t)idx * 4) = o;
}

// ---------------------------------------------------------------------------
extern "C" void kernel_launch(void* const* d_in, const int* in_sizes, int n_in,
                              void* d_out, int out_size, void* d_ws, size_t ws_size,
                              hipStream_t stream) {
  const float* feat_l = (const float*)d_in[0];
  const float* feat_r = (const float*)d_in[1];
  const float* w0 = (const float*)d_in[2];
  const float* b0 = (const float*)d_in[3];
  const float* w1 = (const float*)d_in[4];
  const float* b1 = (const float*)d_in[5];
  const float* w2 = (const float*)d_in[6];
  const float* b2 = (const float*)d_in[7];
  const float* w3 = (const float*)d_in[8];
  const float* b3 = (const float*)d_in[9];
  const float* wf = (const float*)d_in[10];
  const float* bf = (const float*)d_in[11];
  float* out = (float*)d_out;

  // ws layout: A,B = fp16 activation ping-pong [B,H,W,D,4] (50.3 MB each);
  // C = f32 cost volume (25.2 MB); P = f32 pred (2.1 MB); Wh = fp16 weights.
  char* ws = (char*)d_ws;
  hf*    A  = (hf*)ws;
  hf*    Bf = (hf*)(ws + 50331648);
  float* C  = (float*)(ws + 100663296);
  float* P  = (float*)(ws + 125829120);
  hf*    Wh = (hf*)(ws + 127926272);

  dim3 blk(256);
  prep_k<<<dim3(1), blk, 0, stream>>>(w1, w2, w3, wf, Wh);
  cost_volume_k<<<dim3(BB * HHY * (WWX / CVWT) / CVT2), blk, 0, stream>>>(feat_l, feat_r, C);
  conv0_k<<<dim3(HHY * BB), blk, 0, stream>>>(C, w0, b0, A);
  convh_k<4, false><<<dim3(HHY * BB), blk, 0, stream>>>(A,  Wh,        b1, Bf);
  convh_k<4, false><<<dim3(HHY * BB), blk, 0, stream>>>(Bf, Wh + 432,  b2, A);
  convh_k<4, false><<<dim3(HHY * BB), blk, 0, stream>>>(A,  Wh + 864,  b3, Bf);
  convh_k<1, true ><<<dim3(HHY * BB), blk, 0, stream>>>(Bf, Wh + 1296, bf, P);

  const int ngroups = BB * HOUT * (WOUT / 4);
  resize4_k<<<dim3(ngroups / 256), blk, 0, stream>>>(P, out);
}

// Round 19
// 296.290 us; speedup vs baseline: 1.0186x; 1.0119x over previous
//
#include <hip/hip_runtime.h>
#include <cstddef>

// Problem constants (from reference)
#define BB   16
#define HHY  128
#define WWX  256
#define CC   64
#define DDp  12
#define HOUT 1024
#define WOUT 2048

typedef _Float16 hf;                                        // storage type
typedef __fp16 h2 __attribute__((ext_vector_type(2)));      // builtin reg pair

__device__ __forceinline__ h2 u2h(unsigned u) { return __builtin_bit_cast(h2, u); }
__device__ __forceinline__ unsigned pkrtz(float a, float b) {
  return __builtin_bit_cast(unsigned, __builtin_amdgcn_cvt_pkrtz(a, b));
}

#if defined(__has_builtin)
#if __has_builtin(__builtin_amdgcn_fdot2)
#define FDOT2(a, b, c) __builtin_amdgcn_fdot2((a), (b), (c), false)
#endif
#endif
#ifndef FDOT2
#define FDOT2(a, b, c) ((float)(a)[0] * (float)(b)[0] + (float)(a)[1] * (float)(b)[1] + (c))
#endif

// |a-b| dot (1,1) accumulated into c (packed fp16 pairs, f32 accum).
__device__ __forceinline__ float adot(unsigned lu, unsigned ru, float c) {
  const h2 d = u2h(lu) - u2h(ru);
  const unsigned au = __builtin_bit_cast(unsigned, d) & 0x7FFF7FFFu;
  return FDOT2(u2h(au), u2h(0x3C003C00u), c);
}

// ---------------------------------------------------------------------------
// prep: convert conv weights to fp16, repacked [tap27][co][ci] so the ci pairs
// consumed by v_dot2_f32_f16 are contiguous. w1,w2,w3: 432 each; wf: 108.
// ---------------------------------------------------------------------------
__global__ __launch_bounds__(256) void prep_k(const float* __restrict__ w1,
                                              const float* __restrict__ w2,
                                              const float* __restrict__ w3,
                                              const float* __restrict__ wf,
                                              hf* __restrict__ o) {
  const int t = threadIdx.x;
  for (int i = t; i < 432; i += 256) {
    const int t27 = i >> 4;
    const int ci = (i >> 2) & 3;
    const int co = i & 3;
    const int dst = (t27 * 4 + co) * 4 + ci;
    o[dst]       = (hf)w1[i];
    o[432 + dst] = (hf)w2[i];
    o[864 + dst] = (hf)w3[i];
  }
  for (int i = t; i < 108; i += 256) o[1296 + i] = (hf)wf[i];  // [t27][ci], COUT=1
}

// ---------------------------------------------------------------------------
// Kernel 1: cost volume (f32 out) — ROUND-14 VERSION RESTORED (best of 13
// structures: 99-104us, occ 81%). Block = 64-w tile x 12 d; 256 threads =
// 64 w x 4 dgroups, 3 outputs each. fp16 LDS tile (R halo zero-filled),
// 20 KB, 8 blocks/CU. 13 structural variants (occupancy 20-81%, reg/DMA
// staging, single/double buffer, persistent, channel-split, counted vmcnt)
// all land 100-118us: stage->barrier->compute chain serializes the LDS/VALU/
// mem floors (~each 20-40us) to ~100us regardless of shape. Breaking it
// needs producer/consumer wave specialization — out of scope.
// ---------------------------------------------------------------------------
#define CVS 36        // LDS row stride (dwords): 32 data + 4 pad
#define CVHALO 11
#define CVWT 64
#define CVROWS (CVWT + CVHALO + CVWT)  // 75 R rows + 64 L rows = 139

__global__ __launch_bounds__(256, 8) void cost_volume_k(const float* __restrict__ L,
                                                        const float* __restrict__ R,
                                                        float* __restrict__ cost) {
  __shared__ unsigned ls[CVROWS * CVS];   // 139*36*4 = 20016 B
  const int t = threadIdx.x;
  const int wb = blockIdx.x * CVWT;
  const int h = blockIdx.y;
  const int b = blockIdx.z;
  const size_t rowbase = ((size_t)(b * HHY + h)) * WWX;
  const float* Lrow = L + rowbase * CC;
  const float* Rrow = R + rowbase * CC;

  // Stage tile: rows 0..74 = R (global w' = wb-11+row, zero if <0);
  //             rows 75..138 = L (global w = wb+row-75). f32 -> fp16 pairs.
#pragma unroll
  for (int j = 0; j < 9; ++j) {
    const int fi = t + 256 * j;          // float4 id in [0, 2224)
    if (fi < CVROWS * 16) {
      const int row = fi >> 4;
      const int f4 = fi & 15;
      float4 v = make_float4(0.f, 0.f, 0.f, 0.f);
      if (row < CVWT + CVHALO) {
        const int gw = wb - CVHALO + row;
        if (gw >= 0) v = *(const float4*)(Rrow + (size_t)gw * CC + 4 * f4);
      } else {
        const int gw = wb + row - (CVWT + CVHALO);
        v = *(const float4*)(Lrow + (size_t)gw * CC + 4 * f4);
      }
      *(uint2*)(&ls[row * CVS + f4 * 2]) =
          make_uint2(pkrtz(v.x, v.y), pkrtz(v.z, v.w));
    }
  }
  __syncthreads();

  const int w = t & 63;
  const int dg = t >> 6;                 // wave-uniform
  const int rb0 = (w + CVHALO - dg) * CVS;
  const int rb1 = rb0 - 4 * CVS;
  const int rb2 = rb0 - 8 * CVS;
  const int rbL = (CVWT + CVHALO + w) * CVS;

  float a0 = 0.f, a1 = 0.f, a2 = 0.f;
#pragma unroll
  for (int k = 0; k < 8; ++k) {
    const uint4 lq = *(const uint4*)(&ls[rbL + 4 * k]);
    const uint4 r0 = *(const uint4*)(&ls[rb0 + 4 * k]);
    a0 = adot(lq.x, r0.x, a0); a0 = adot(lq.y, r0.y, a0);
    a0 = adot(lq.z, r0.z, a0); a0 = adot(lq.w, r0.w, a0);
    const uint4 r1 = *(const uint4*)(&ls[rb1 + 4 * k]);
    a1 = adot(lq.x, r1.x, a1); a1 = adot(lq.y, r1.y, a1);
    a1 = adot(lq.z, r1.z, a1); a1 = adot(lq.w, r1.w, a1);
    const uint4 r2 = *(const uint4*)(&ls[rb2 + 4 * k]);
    a2 = adot(lq.x, r2.x, a2); a2 = adot(lq.y, r2.y, a2);
    a2 = adot(lq.z, r2.z, a2); a2 = adot(lq.w, r2.w, a2);
  }

  // Transpose through LDS for coalesced output stores.
  __syncthreads();                       // tile reads done before overwrite
  float* lo = (float*)ls;
  lo[w * DDp + dg]     = a0;
  lo[w * DDp + dg + 4] = a1;
  lo[w * DDp + dg + 8] = a2;
  __syncthreads();
  if (t < CVWT * DDp / 4) {              // 192 float4
    const float4 v = *(const float4*)(&lo[4 * t]);
    *(float4*)(cost + (rowbase + wb) * DDp + 4 * t) = v;
  }
}

// ---------------------------------------------------------------------------
// conv0: 3x3x3, CIN=1 (f32 cost) -> COUT=4 (fp16 out). Block = one (b,h) row
// (XCD h-remap), thread = w. Row staged f32 in LDS stride 20; weights (108 f)
// wave-uniform global loads; fp16 pack on store. (Round-10 version — best.)
// ---------------------------------------------------------------------------
__global__ __launch_bounds__(256) void conv0_k(const float* __restrict__ x,
                                               const float* __restrict__ wt,
                                               const float* __restrict__ bs,
                                               hf* __restrict__ y) {
  constexpr int S = 20;
  __shared__ float ls[WWX * S];   // 20 KB
  const int t = threadIdx.x;
  const int id = blockIdx.x;
  const int h = ((id & 7) << 4) | ((id >> 3) & 15);  // XCD-contiguous h chunks
  const int b = id >> 7;

  float acc[DDp][4];
#pragma unroll
  for (int co = 0; co < 4; ++co) {
    const float bv = bs[co];
#pragma unroll
    for (int d = 0; d < DDp; ++d) acc[d][co] = bv;
  }

#pragma unroll
  for (int kh = 0; kh < 3; ++kh) {
    const int hh = h + kh - 1;
    if (hh < 0 || hh >= HHY) continue;  // block-uniform

    __syncthreads();
    const float* xr = x + ((size_t)(b * HHY + hh) * WWX) * DDp;
#pragma unroll
    for (int j = 0; j < 3; ++j) {
      const int fi4 = t + 256 * j;     // [0,768)
      const int w_ = fi4 / 3;
      const int k_ = fi4 - w_ * 3;
      *(float4*)(&ls[w_ * S + k_ * 4]) = ((const float4*)xr)[fi4];
    }
    __syncthreads();

#pragma unroll
    for (int kw = 0; kw < 3; ++kw) {
      const int ww = t + kw - 1;
      if (ww < 0 || ww >= WWX) continue;
      const float* lp = &ls[ww * S];

      const float* wp = wt + (size_t)(kh * 3 + kw) * 12;
      float wr[12];
#pragma unroll
      for (int i = 0; i < 12; ++i) wr[i] = wp[i];

      float v[DDp];
#pragma unroll
      for (int k = 0; k < 3; ++k)
        ((float4*)v)[k] = *(const float4*)(lp + 4 * k);
#pragma unroll
      for (int vo = 0; vo < DDp; ++vo)
#pragma unroll
        for (int kd = 0; kd < 3; ++kd) {
          const int d = vo + 1 - kd;
          if (d < 0 || d >= DDp) continue;
#pragma unroll
          for (int co = 0; co < 4; ++co)
            acc[d][co] += v[vo] * wr[kd * 4 + co];
        }
    }
  }

  unsigned ov[DDp * 2];
#pragma unroll
  for (int d = 0; d < DDp; ++d) {
    ov[d * 2]     = pkrtz(fmaxf(acc[d][0], 0.f), fmaxf(acc[d][1], 0.f));
    ov[d * 2 + 1] = pkrtz(fmaxf(acc[d][2], 0.f), fmaxf(acc[d][3], 0.f));
  }
  uint4* yp = (uint4*)(y + ((size_t)(b * HHY + h) * WWX + t) * (DDp * 4));
#pragma unroll
  for (int i = 0; i < 6; ++i) yp[i] = ((uint4*)ov)[i];
}

// ---------------------------------------------------------------------------
// Mid/final conv3d 3x3x3, CIN=4, fp16 activations [B,H,W,D,4], f32 accumulate
// via v_dot2_f32_f16. Block = one (b,h) row (XCD h-remap), thread = w. Rows
// staged fp16 in LDS (26-uint stride; 26.6 KB -> 6 blocks/CU). Weights fp16
// repacked [tap][co][ci], wave-uniform scalar loads. (Round-10 version.)
// FUSE_SM: COUT=1 final conv + softmax(-cost) + disparity regression.
// ---------------------------------------------------------------------------
template <int COUT, bool FUSE_SM>
__global__ __launch_bounds__(256) void convh_k(const hf* __restrict__ x,
                                               const hf* __restrict__ wh,
                                               const float* __restrict__ bs,
                                               void* __restrict__ yv) {
  constexpr int DCH = DDp * 4;        // 48 halves per w
  constexpr int SU  = 26;             // LDS stride per w in uints (52 halves)
  __shared__ unsigned lsu[WWX * SU];  // 26624 B

  const int t = threadIdx.x;
  const int id = blockIdx.x;
  const int h = ((id & 7) << 4) | ((id >> 3) & 15);
  const int b = id >> 7;

  float acc[DDp][COUT];
#pragma unroll
  for (int co = 0; co < COUT; ++co) {
    const float bv = bs[co];
#pragma unroll
    for (int d = 0; d < DDp; ++d) acc[d][co] = bv;
  }

  const unsigned* whu = (const unsigned*)wh;

#pragma unroll
  for (int kh = 0; kh < 3; ++kh) {
    const int hh = h + kh - 1;
    if (hh < 0 || hh >= HHY) continue;  // block-uniform

    __syncthreads();
    const uint4* xr = (const uint4*)(x + (size_t)(b * HHY + hh) * WWX * DCH);
#pragma unroll
    for (int j = 0; j < 6; ++j) {
      const int fi4 = t + 256 * j;     // [0,1536)
      const int w_ = fi4 / 6;
      const int k_ = fi4 - w_ * 6;
      const uint4 v = xr[fi4];
      unsigned* dst = &lsu[w_ * SU + k_ * 4];
      *(uint2*)(dst)     = make_uint2(v.x, v.y);
      *(uint2*)(dst + 2) = make_uint2(v.z, v.w);
    }
    __syncthreads();

#pragma unroll
    for (int kw = 0; kw < 3; ++kw) {
      const int ww = t + kw - 1;
      if (ww < 0 || ww >= WWX) continue;  // divergent only at row edges

      // per-tap fp16 weights, wave-uniform scalar loads
      unsigned w01[3][COUT], w23[3][COUT];
      const int tap3 = (kh * 3 + kw) * 3;
#pragma unroll
      for (int kd = 0; kd < 3; ++kd)
#pragma unroll
        for (int co = 0; co < COUT; ++co) {
          const int u0 = ((tap3 + kd) * COUT + co) * 2;
          w01[kd][co] = whu[u0];
          w23[kd][co] = whu[u0 + 1];
        }

      const unsigned* lp = &lsu[ww * SU];
#pragma unroll
      for (int vo = 0; vo < DDp; ++vo) {
        const uint2 xu = *(const uint2*)(lp + vo * 2);
        const h2 x01 = u2h(xu.x), x23 = u2h(xu.y);
#pragma unroll
        for (int kd = 0; kd < 3; ++kd) {
          const int d = vo + 1 - kd;
          if (d < 0 || d >= DDp) continue;
#pragma unroll
          for (int co = 0; co < COUT; ++co)
            acc[d][co] = FDOT2(x01, u2h(w01[kd][co]),
                         FDOT2(x23, u2h(w23[kd][co]), acc[d][co]));
        }
      }
    }
  }

  if constexpr (FUSE_SM) {
    float* y = (float*)yv;
    float mn = acc[0][0];
#pragma unroll
    for (int d = 1; d < DDp; ++d) mn = fminf(mn, acc[d][0]);
    float s = 0.f, sw = 0.f;
#pragma unroll
    for (int d = 0; d < DDp; ++d) {
      const float e = __expf(mn - acc[d][0]);
      s += e;
      sw += e * (float)d;
    }
    y[(size_t)(b * HHY + h) * WWX + t] = sw / s;
  } else {
    hf* y = (hf*)yv;
    unsigned ov[DDp * 2];
#pragma unroll
    for (int d = 0; d < DDp; ++d) {
      ov[d * 2]     = pkrtz(fmaxf(acc[d][0], 0.f), fmaxf(acc[d][1 % COUT], 0.f));
      ov[d * 2 + 1] = pkrtz(fmaxf(acc[d][2 % COUT], 0.f), fmaxf(acc[d][3 % COUT], 0.f));
    }
    uint4* yp = (uint4*)(y + ((size_t)(b * HHY + h) * WWX + t) * DCH);
#pragma unroll
    for (int i = 0; i < 6; ++i) yp[i] = ((uint4*)ov)[i];
  }
}

// ---------------------------------------------------------------------------
// 8x bilinear upsample, 4 outputs per thread (2 input cols x 2 rows -> 4 loads,
// 1 float4 store). jax half-pixel convention; edge renorm == index clamp.
// At floor: 6.1 TB/s effective (134 MB write-dominated).
// ---------------------------------------------------------------------------
__global__ __launch_bounds__(256) void resize4_k(const float* __restrict__ pred,
                                                 float* __restrict__ out) {
  const int idx = blockIdx.x * 256 + threadIdx.x;
  const int xg = idx & 511;
  const int y = (idx >> 9) & 1023;
  const int b = idx >> 19;

  const int parity = xg & 1;
  const int m = xg >> 1;
  const int x0 = m - 1 + parity;
  const int x0c = max(x0, 0);
  const int x1c = min(x0 + 1, WWX - 1);
  const float wx0 = (parity ? 0.0625f : 0.5625f);

  const int py = y & 7;
  const int my = y >> 3;
  const int y0 = my - 1 + (py >= 4 ? 1 : 0);
  const float wy = (py >= 4) ? 0.0625f + (py - 4) * 0.125f : 0.5625f + py * 0.125f;
  const int y0c = max(y0, 0);
  const int y1c = min(y0 + 1, HHY - 1);

  const float* pb = pred + (size_t)b * HHY * WWX;
  const float a = pb[y0c * WWX + x0c];
  const float bv = pb[y0c * WWX + x1c];
  const float c = pb[y1c * WWX + x0c];
  const float d = pb[y1c * WWX + x1c];

  const float top0 = a + (bv - a) * wx0;
  const float bot0 = c + (d - c) * wx0;
  const float dtop = (bv - a) * 0.125f;
  const float dbot = (d - c) * 0.125f;

  float4 o;
  o.x = top0 + wy * (bot0 - top0);
  o.y = (top0 + dtop) + wy * ((bot0 + dbot) - (top0 + dtop));
  o.z = (top0 + 2.f * dtop) + wy * ((bot0 + 2.f * dbot) - (top0 + 2.f * dtop));
  o.w = (top0 + 3.f * dtop) + wy * ((bot0 + 3.f * dbot) - (top0 + 3.f * dtop));

  *(float4*)(out + (size_t)idx * 4) = o;
}

// ---------------------------------------------------------------------------
extern "C" void kernel_launch(void* const* d_in, const int* in_sizes, int n_in,
                              void* d_out, int out_size, void* d_ws, size_t ws_size,
                              hipStream_t stream) {
  const float* feat_l = (const float*)d_in[0];
  const float* feat_r = (const float*)d_in[1];
  const float* w0 = (const float*)d_in[2];
  const float* b0 = (const float*)d_in[3];
  const float* w1 = (const float*)d_in[4];
  const float* b1 = (const float*)d_in[5];
  const float* w2 = (const float*)d_in[6];
  const float* b2 = (const float*)d_in[7];
  const float* w3 = (const float*)d_in[8];
  const float* b3 = (const float*)d_in[9];
  const float* wf = (const float*)d_in[10];
  const float* bf = (const float*)d_in[11];
  float* out = (float*)d_out;

  // ws layout: A,B = fp16 activation ping-pong [B,H,W,D,4] (50.3 MB each);
  // C = f32 cost volume (25.2 MB); P = f32 pred (2.1 MB); Wh = fp16 weights.
  char* ws = (char*)d_ws;
  hf*    A  = (hf*)ws;
  hf*    Bf = (hf*)(ws + 50331648);
  float* C  = (float*)(ws + 100663296);
  float* P  = (float*)(ws + 125829120);
  hf*    Wh = (hf*)(ws + 127926272);

  dim3 blk(256);
  prep_k<<<dim3(1), blk, 0, stream>>>(w1, w2, w3, wf, Wh);
  cost_volume_k<<<dim3(WWX / CVWT, HHY, BB), blk, 0, stream>>>(feat_l, feat_r, C);
  conv0_k<<<dim3(HHY * BB), blk, 0, stream>>>(C, w0, b0, A);
  convh_k<4, false><<<dim3(HHY * BB), blk, 0, stream>>>(A,  Wh,        b1, Bf);
  convh_k<4, false><<<dim3(HHY * BB), blk, 0, stream>>>(Bf, Wh + 432,  b2, A);
  convh_k<4, false><<<dim3(HHY * BB), blk, 0, stream>>>(A,  Wh + 864,  b3, Bf);
  convh_k<1, true ><<<dim3(HHY * BB), blk, 0, stream>>>(Bf, Wh + 1296, bf, P);

  const int ngroups = BB * HOUT * (WOUT / 4);
  resize4_k<<<dim3(ngroups / 256), blk, 0, stream>>>(P, out);
}